// Round 16
// baseline (164.664 us; speedup 1.0000x reference)
//
#include <hip/hip_runtime.h>
#include <hip/hip_bf16.h>

#define T_TOKENS 2048
#define D_EMBD 768
#define N_EXP 64
#define EW 256
#define TOPK 8
#define TW (N_EXP*EW)
#define PAD_SLOTS 24576   // 16384 + 64*127 rounded up (128-row tiles)
#define SCHED_MAX 192     // sum ceil(count/128) <= 128 + 64
#define OUT_BASE (2048*768)

typedef __attribute__((ext_vector_type(8))) short bf16x8;
typedef __attribute__((ext_vector_type(4))) float f32x4;

typedef __attribute__((address_space(1))) void GAS;
typedef __attribute__((address_space(3))) void LAS;
#define GLOAD16(g, l) __builtin_amdgcn_global_load_lds((GAS*)(g), (LAS*)(l), 16, 0, 0)

__device__ inline unsigned short f2bu(float f) {
  union { __hip_bfloat16 b; unsigned short u; } cv; cv.b = __float2bfloat16(f); return cv.u;
}

// ---------------- init ----------------
__global__ void k_init(int* counts, int* cursor, float* psum, float* scal,
                       float* wgt_slot, int* tok_slot, int* sched_e) {
  int i = blockIdx.x*256 + threadIdx.x;   // 24576 threads
  if (i < N_EXP) { counts[i] = 0; cursor[i] = 0; psum[i] = 0.f; }
  if (i < 2) scal[i] = 0.f;
  if (i < PAD_SLOTS) { wgt_slot[i] = 0.f; tok_slot[i] = 0; }
  if (i < SCHED_MAX) sched_e[i] = -1;
}

// ---------------- x -> bf16 ----------------
__global__ void k_cvt_x(const float* __restrict__ x, __hip_bfloat16* __restrict__ xb) {
  int i = blockIdx.x*256 + threadIdx.x;   // 393216 float4
  float4 v = reinterpret_cast<const float4*>(x)[i];
  ushort4 o;
  o.x = f2bu(v.x); o.y = f2bu(v.y); o.z = f2bu(v.z); o.w = f2bu(v.w);
  reinterpret_cast<ushort4*>(xb)[i] = o;
}

// ---------------- repack w1 [768][16384] f32 -> w1p[e][kc<12][n<256][k8<64] bf16 ----
// block (kc*64 + e): reads 64 rows x 1KB windows (consecutive blocks = same kc,
// different e -> together cover full 64KB rows); contiguous 32KB panel write.
__global__ __launch_bounds__(256) void k_repack1(const float* __restrict__ w1,
                                                 __hip_bfloat16* __restrict__ w1p) {
  __shared__ unsigned short t[256][72];   // [n][k8], pad 72 (16B-aligned rows)
  int e = blockIdx.x & 63, kc = blockIdx.x >> 6;
  int tid = threadIdx.x;
  int r = tid >> 2, cq = tid & 3;         // row 0..63, col-quarter
  const float4* src = reinterpret_cast<const float4*>(
      w1 + (size_t)(kc*64 + r)*TW + e*256 + cq*64);
  #pragma unroll
  for (int i = 0; i < 16; i++) {
    float4 v = src[i];
    int c = cq*64 + i*4;
    t[c+0][r] = f2bu(v.x); t[c+1][r] = f2bu(v.y);
    t[c+2][r] = f2bu(v.z); t[c+3][r] = f2bu(v.w);
  }
  __syncthreads();
  int n = tid;                            // 256 output rows
  __hip_bfloat16* dst = w1p + (size_t)(e*12 + kc)*16384 + n*64;
  const uint4* row = reinterpret_cast<const uint4*>(&t[n][0]);
  #pragma unroll
  for (int j = 0; j < 8; j++)
    reinterpret_cast<uint4*>(dst)[j] = row[j];
}

// ---------------- repack w2 [16384][768] f32 -> w2p[e][kc<4][n<768][k8<64] bf16 ----
// block (e*4 + kc): reads 64 FULL rows (192KB contiguous); 96KB contiguous write.
__global__ __launch_bounds__(256) void k_repack2(const float* __restrict__ w2,
                                                 __hip_bfloat16* __restrict__ w2p) {
  __shared__ unsigned short t[768][72];   // 110.6 KB
  int e = blockIdx.x >> 2, kc = blockIdx.x & 3;
  int tid = threadIdx.x;
  const float* base = w2 + (size_t)(e*256 + kc*64)*D_EMBD;
  for (int it = 0; it < 48; it++) {
    int idx = it*256 + tid;               // 64 rows x 192 float4
    int r = idx / 192, c4 = idx - r*192;
    float4 v = *reinterpret_cast<const float4*>(base + (size_t)r*D_EMBD + c4*4);
    int c = c4*4;
    t[c+0][r] = f2bu(v.x); t[c+1][r] = f2bu(v.y);
    t[c+2][r] = f2bu(v.z); t[c+3][r] = f2bu(v.w);
  }
  __syncthreads();
  #pragma unroll
  for (int pass = 0; pass < 3; pass++) {
    int n = pass*256 + tid;
    __hip_bfloat16* dst = w2p + (size_t)(e*4 + kc)*49152 + n*64;
    const uint4* row = reinterpret_cast<const uint4*>(&t[n][0]);
    #pragma unroll
    for (int j = 0; j < 8; j++)
      reinterpret_cast<uint4*>(dst)[j] = row[j];
  }
}

// ---------------- router logits GEMM: lp[kc][t][e] partial sums ----------------
__global__ __launch_bounds__(256) void k_logits(const float* __restrict__ x,
                                                const float* __restrict__ rw,
                                                float* __restrict__ lp) {
  __shared__ float rw_s[8][256];
  int tid = threadIdx.x;
  int tg = blockIdx.x, eg = blockIdx.y, kc = blockIdx.z;
  #pragma unroll
  for (int idx = 0; idx < 8; idx++)
    rw_s[idx][tid] = rw[(size_t)(eg*8 + idx)*D_EMBD + kc*256 + tid];
  __syncthreads();
  int tok = tg*256 + tid;
  const float4* x4 = reinterpret_cast<const float4*>(x + (size_t)tok*D_EMBD + kc*256);
  float acc[8];
  #pragma unroll
  for (int e = 0; e < 8; e++) acc[e] = 0.f;
  #pragma unroll 4
  for (int k4 = 0; k4 < 64; k4++) {
    float4 xv = x4[k4];
    #pragma unroll
    for (int e = 0; e < 8; e++)
      acc[e] += xv.x*rw_s[e][k4*4+0] + xv.y*rw_s[e][k4*4+1]
              + xv.z*rw_s[e][k4*4+2] + xv.w*rw_s[e][k4*4+3];
  }
  float* dst = lp + (size_t)kc*T_TOKENS*N_EXP + (size_t)tok*N_EXP + eg*8;
  float4 o0 = {acc[0], acc[1], acc[2], acc[3]};
  float4 o1 = {acc[4], acc[5], acc[6], acc[7]};
  reinterpret_cast<float4*>(dst)[0] = o0;
  reinterpret_cast<float4*>(dst)[1] = o1;
}

// ---------------- router part 2: sigmoid, parallel-rank top-8, losses ----------------
__global__ __launch_bounds__(256) void k_router2(const float* __restrict__ lp,
                          int* __restrict__ sel_e, float* __restrict__ sel_w,
                          int* __restrict__ counts, float* __restrict__ psum,
                          float* __restrict__ scal) {
  __shared__ float psum_s[4][64];
  __shared__ int cnt_s[4][64];
  int tid = threadIdx.x, wv = tid >> 6, lane = tid & 63;
  float pacc = 0.f, zacc = 0.f;
  int cacc = 0;
  int tbase = blockIdx.x*8 + wv*2;
  #pragma unroll
  for (int it = 0; it < 2; it++) {
    int t = tbase + it;
    float logit = lp[(size_t)t*N_EXP + lane]
                + lp[(size_t)T_TOKENS*N_EXP + (size_t)t*N_EXP + lane]
                + lp[2*(size_t)T_TOKENS*N_EXP + (size_t)t*N_EXP + lane];
    float prob = 1.f/(1.f + expf(-logit));
    pacc += prob;
    float mx = logit;
    for (int s = 32; s; s >>= 1) mx = fmaxf(mx, __shfl_xor(mx, s, 64));
    float sse = expf(logit - mx);
    for (int s = 32; s; s >>= 1) sse += __shfl_xor(sse, s, 64);
    float lse = mx + logf(sse);
    zacc += lse*lse;
    int rank = 0;
    #pragma unroll
    for (int j = 0; j < 64; j++) {
      float pj = __shfl(prob, j, 64);
      rank += (pj > prob || (pj == prob && j < lane)) ? 1 : 0;
    }
    bool sel = rank < TOPK;
    float sp = sel ? prob : 0.f;
    for (int s = 32; s; s >>= 1) sp += __shfl_xor(sp, s, 64);
    if (sel) {
      sel_e[t*TOPK + rank] = lane;
      sel_w[t*TOPK + rank] = prob / (sp + 1e-20f);
      cacc++;
    }
  }
  psum_s[wv][lane] = pacc;
  cnt_s[wv][lane] = cacc;
  if (lane == 0) atomicAdd(&scal[0], zacc);
  __syncthreads();
  if (tid < 64) {
    float p = psum_s[0][tid] + psum_s[1][tid] + psum_s[2][tid] + psum_s[3][tid];
    int c = cnt_s[0][tid] + cnt_s[1][tid] + cnt_s[2][tid] + cnt_s[3][tid];
    atomicAdd(&psum[tid], p);
    atomicAdd(&counts[tid], c);
  }
}

// ---------------- schedule: 128-row tiles, linear positions ----------------
__global__ void k_schedule(const int* __restrict__ counts, int* __restrict__ offsets,
                           int* __restrict__ sched_e, int* __restrict__ sched_r0) {
  int e = threadIdx.x;   // 64 threads, one wave
  int c = counts[e];
  int tiles = (c + 127) >> 7;
  int padded = tiles << 7;
  int ip = padded;
  for (int s = 1; s < 64; s <<= 1) { int v = __shfl_up(ip, s, 64); if (e >= s) ip += v; }
  int rowoff = ip - padded;
  offsets[e] = rowoff;
  int it = tiles;
  for (int s = 1; s < 64; s <<= 1) { int v = __shfl_up(it, s, 64); if (e >= s) it += v; }
  int rank = it - tiles;
  for (int i = 0; i < tiles; i++) {
    sched_e[rank + i] = e;
    sched_r0[rank + i] = rowoff + i*128;
  }
}

// ---------------- assign tokens to slots ----------------
__global__ void k_assign(const int* __restrict__ sel_e, const float* __restrict__ sel_w,
                         const int* __restrict__ offsets, int* __restrict__ cursor,
                         int* __restrict__ tok_slot, float* __restrict__ wgt_slot,
                         int* __restrict__ slot_tk) {
  int i = blockIdx.x*256 + threadIdx.x;   // 16384
  int e = sel_e[i];
  int pos = atomicAdd(&cursor[e], 1);
  int slot = offsets[e] + pos;
  tok_slot[slot] = i >> 3;
  wgt_slot[slot] = sel_w[i];
  slot_tk[i] = slot;
}

// ---------------- grouped GEMM: 128x128 tile, BK=64, bf16 both sides ----------------
// B from contiguous repacked panels (16KB/step window) via global_load_lds.
// MODE 1: A = xb gathered -> h = relu(x@W1_e)^2*gate  (NS=12, grid (192,2))
// MODE 2: A = hprm        -> y = h@W2_e               (NS=4,  grid (192,6))
template<int MODE>
__global__ __launch_bounds__(256) void k_moe_gemm(
    const __hip_bfloat16* __restrict__ Ab, const __hip_bfloat16* __restrict__ Bp,
    const int* __restrict__ sched_e, const int* __restrict__ sched_r0,
    const int* __restrict__ tok_slot, const float* __restrict__ wgt_slot,
    __hip_bfloat16* __restrict__ outp) {
  constexpr int NS    = (MODE == 1) ? 12 : 4;
  constexpr int NKC   = (MODE == 1) ? 12 : 4;
  constexpr int PANEL = (MODE == 1) ? 16384 : 49152;
  __shared__ __hip_bfloat16 As[2][128*64];   // 16 KB each
  __shared__ __hip_bfloat16 Bs[2][128*64];
  int tid = threadIdx.x;
  int nch = blockIdx.y;
  int arow = tid >> 3, akc = tid & 7;
  int wv = tid >> 6, lane = tid & 63;
  int wm = wv >> 1, wn = wv & 1;
  int l15 = lane & 15, l4 = lane >> 4;

  int p = blockIdx.x;
  int e = sched_e[p];
  if (e < 0) return;
  int r0 = sched_r0[p];

  size_t pb0 = (size_t)(e*NKC)*PANEL + (nch*128)*64;

  size_t abase[4];
  int aswz[4];
  #pragma unroll
  for (int i = 0; i < 4; i++) {
    int row = i*32 + arow;
    if (MODE == 1) abase[i] = (size_t)tok_slot[r0 + row] * D_EMBD;
    else           abase[i] = (size_t)(r0 + row) * EW;
    aswz[i] = (akc ^ (row & 7))*8;
  }

  auto STAGE = [&](int bsel, int step) {
    int k0 = step*64;
    size_t pb = pb0 + (size_t)step*PANEL;   // panel for kc=step
    #pragma unroll
    for (int i = 0; i < 4; i++) {
      GLOAD16(Ab + abase[i] + k0 + aswz[i], &As[bsel][0] + (i*256 + tid)*8);
      GLOAD16(Bp + pb + (i*32 + arow)*64 + aswz[i], &Bs[bsel][0] + (i*256 + tid)*8);
    }
  };

  f32x4 acc[4][4];
  f32x4 z = {0.f, 0.f, 0.f, 0.f};
  #pragma unroll
  for (int m = 0; m < 4; m++)
    #pragma unroll
    for (int n = 0; n < 4; n++) acc[m][n] = z;

  auto COMPUTE = [&](int bsel) {
    const char* asC = (const char*)&As[bsel][0];
    const char* bsC = (const char*)&Bs[bsel][0];
    bf16x8 af[4][2], bq[4][2];
    #pragma unroll
    for (int m = 0; m < 4; m++) {
      int ra = wm*64 + m*16 + l15;
      #pragma unroll
      for (int kk = 0; kk < 2; kk++)
        af[m][kk] = *reinterpret_cast<const bf16x8*>(
            asC + ra*128 + (((kk*4 + l4) ^ (ra & 7)) << 4));
    }
    #pragma unroll
    for (int n = 0; n < 4; n++) {
      int rb = wn*64 + n*16 + l15;
      #pragma unroll
      for (int kk = 0; kk < 2; kk++)
        bq[n][kk] = *reinterpret_cast<const bf16x8*>(
            bsC + rb*128 + (((kk*4 + l4) ^ (rb & 7)) << 4));
    }
    #pragma unroll
    for (int kk = 0; kk < 2; kk++)
      #pragma unroll
      for (int m = 0; m < 4; m++)
        #pragma unroll
        for (int n = 0; n < 4; n++)
          acc[m][n] = __builtin_amdgcn_mfma_f32_16x16x32_bf16(af[m][kk], bq[n][kk], acc[m][n], 0, 0, 0);
  };

  STAGE(0, 0);
  asm volatile("s_waitcnt vmcnt(0)" ::: "memory");
  __syncthreads();

  int cur = 0;
  for (int step = 0; step < NS; step++) {
    bool more = (step + 1 < NS);
    if (more) STAGE(cur ^ 1, step + 1);
    COMPUTE(cur);
    asm volatile("s_waitcnt vmcnt(0)" ::: "memory");
    __syncthreads();
    cur ^= 1;
  }

  if (MODE == 1) {
    #pragma unroll
    for (int m = 0; m < 4; m++)
      #pragma unroll
      for (int j = 0; j < 4; j++) {
        int r = r0 + wm*64 + m*16 + l4*4 + j;
        float wg = wgt_slot[r];
        #pragma unroll
        for (int n = 0; n < 4; n++) {
          int col = nch*128 + wn*64 + n*16 + l15;
          float v = fmaxf(acc[m][n][j], 0.f);
          outp[(size_t)r*EW + col] = __float2bfloat16(v*v*wg);
        }
      }
  } else {
    #pragma unroll
    for (int m = 0; m < 4; m++)
      #pragma unroll
      for (int j = 0; j < 4; j++) {
        int r = r0 + wm*64 + m*16 + l4*4 + j;
        #pragma unroll
        for (int n = 0; n < 4; n++) {
          int col = nch*128 + wn*64 + n*16 + l15;
          outp[(size_t)r*D_EMBD + col] = __float2bfloat16(acc[m][n][j]);
        }
      }
  }
}

// ---------------- combine 8 expert rows per token (vectorized gather) ----------------
__global__ void k_combine(const __hip_bfloat16* __restrict__ y, const int* __restrict__ slot_tk,
                          float* __restrict__ out) {
  __shared__ int s[TOPK];
  int t = blockIdx.x, tid = threadIdx.x;
  if (tid < TOPK) s[tid] = slot_tk[t*TOPK + tid];
  __syncthreads();
  if (tid < 192) {
    int c = tid*4;
    float a0 = 0.f, a1 = 0.f, a2 = 0.f, a3 = 0.f;
    #pragma unroll
    for (int k = 0; k < TOPK; k++) {
      ushort4 v = *reinterpret_cast<const ushort4*>(&y[(size_t)s[k]*D_EMBD + c]);
      union { unsigned int u; float f; } f0, f1, f2, f3;
      f0.u = ((unsigned int)v.x) << 16;
      f1.u = ((unsigned int)v.y) << 16;
      f2.u = ((unsigned int)v.z) << 16;
      f3.u = ((unsigned int)v.w) << 16;
      a0 += f0.f; a1 += f1.f; a2 += f2.f; a3 += f3.f;
    }
    float4 o = {a0, a1, a2, a3};
    *reinterpret_cast<float4*>(&out[(size_t)t*D_EMBD + c]) = o;
  }
}

// ---------------- aux losses + f_i ----------------
__global__ void k_finalize(const int* __restrict__ counts, const float* __restrict__ psum,
                           const float* __restrict__ scal, float* __restrict__ out) {
  __shared__ float part[N_EXP], ptot[N_EXP];
  int e = threadIdx.x;
  float f = (float)counts[e] / 16384.f;
  float p = psum[e] / 2048.f;
  part[e] = f * p;
  ptot[e] = p;
  out[OUT_BASE + 3 + e] = f;
  __syncthreads();
  if (e == 0) {
    float s = 0.f, q = 0.f;
    for (int i = 0; i < N_EXP; i++) { s += part[i]; q += ptot[i]; }
    out[OUT_BASE + 0] = scal[0] / 2048.f;      // router_z_loss
    out[OUT_BASE + 1] = 64.f * s;              // load_balance_loss
    out[OUT_BASE + 2] = q;                     // compute_loss
  }
}

extern "C" void kernel_launch(void* const* d_in, const int* in_sizes, int n_in,
                              void* d_out, int out_size, void* d_ws, size_t ws_size,
                              hipStream_t stream) {
  const float* x  = (const float*)d_in[0];
  const float* rw = (const float*)d_in[1];
  const float* w1 = (const float*)d_in[2];
  const float* w2 = (const float*)d_in[3];
  float* out = (float*)d_out;
  char* ws = (char*)d_ws;

  size_t o = 0;
  auto alloc = [&](size_t b) { size_t r = o; o += (b + 255) & ~(size_t)255; return r; };
  __hip_bfloat16* xb   = (__hip_bfloat16*)(ws + alloc(2048UL*768*2));
  __hip_bfloat16* w1p  = (__hip_bfloat16*)(ws + alloc(768UL*16384*2));
  __hip_bfloat16* w2p  = (__hip_bfloat16*)(ws + alloc(16384UL*768*2));
  __hip_bfloat16* hprm = (__hip_bfloat16*)(ws + alloc((size_t)PAD_SLOTS*256*2));
  __hip_bfloat16* yprm = (__hip_bfloat16*)(ws + alloc((size_t)PAD_SLOTS*768*2));
  float* lp      = (float*)(ws + alloc(3UL*2048*64*4));
  int*   sel_e   = (int*)  (ws + alloc(16384UL*4));
  float* sel_w   = (float*)(ws + alloc(16384UL*4));
  int*   slot_tk = (int*)  (ws + alloc(16384UL*4));
  int*   tokslot = (int*)  (ws + alloc((size_t)PAD_SLOTS*4));
  float* wgtslot = (float*)(ws + alloc((size_t)PAD_SLOTS*4));
  int*   counts  = (int*)  (ws + alloc(256));
  int*   cursor  = (int*)  (ws + alloc(256));
  float* psum    = (float*)(ws + alloc(256));
  float* scal    = (float*)(ws + alloc(256));
  int*   offsets = (int*)  (ws + alloc(256));
  int*   sch_e   = (int*)  (ws + alloc(SCHED_MAX*4));
  int*   sch_r0  = (int*)  (ws + alloc(SCHED_MAX*4));

  k_init<<<96, 256, 0, stream>>>(counts, cursor, psum, scal, wgtslot, tokslot, sch_e);
  k_cvt_x<<<1536, 256, 0, stream>>>(x, xb);
  k_repack1<<<768, 256, 0, stream>>>(w1, w1p);
  k_repack2<<<256, 256, 0, stream>>>(w2, w2p);
  k_logits<<<dim3(8, 8, 3), 256, 0, stream>>>(x, rw, lp);
  k_router2<<<256, 256, 0, stream>>>(lp, sel_e, sel_w, counts, psum, scal);
  k_schedule<<<1, 64, 0, stream>>>(counts, offsets, sch_e, sch_r0);
  k_assign<<<64, 256, 0, stream>>>(sel_e, sel_w, offsets, cursor, tokslot, wgtslot, slot_tk);
  k_moe_gemm<1><<<dim3(SCHED_MAX, 2), 256, 0, stream>>>(xb, w1p, sch_e, sch_r0, tokslot, wgtslot, hprm);
  k_moe_gemm<2><<<dim3(SCHED_MAX, 6), 256, 0, stream>>>(hprm, w2p, sch_e, sch_r0, tokslot, wgtslot, yprm);
  k_combine<<<2048, 256, 0, stream>>>(yprm, slot_tk, out);
  k_finalize<<<1, 64, 0, stream>>>(counts, psum, scal, out);
}

// Round 17
// 152.100 us; speedup vs baseline: 1.0826x; 1.0826x over previous
//
#include <hip/hip_runtime.h>
#include <hip/hip_bf16.h>

#define T_TOKENS 2048
#define D_EMBD 768
#define N_EXP 64
#define EW 256
#define TOPK 8
#define TW (N_EXP*EW)
#define PAD_SLOTS 20480   // 16384 + 64*63 rounded up to 64-tile granularity
#define SCHED_MAX 2560    // 8 * 320 XCD-grouped positions
#define OUT_BASE (2048*768)

typedef __attribute__((ext_vector_type(8))) short bf16x8;
typedef __attribute__((ext_vector_type(4))) float f32x4;

__device__ inline unsigned short f2bu(float f) {
  union { __hip_bfloat16 b; unsigned short u; } cv; cv.b = __float2bfloat16(f); return cv.u;
}
__device__ inline unsigned int pk2(float a, float b) {
  return (unsigned int)f2bu(a) | ((unsigned int)f2bu(b) << 16);
}

// ---------------- init ----------------
__global__ void k_init(int* counts, int* cursor, float* psum, float* scal,
                       float* wgt_slot, int* tok_slot, int* sched_e) {
  int i = blockIdx.x*256 + threadIdx.x;   // 20480 threads
  if (i < N_EXP) { counts[i] = 0; cursor[i] = 0; psum[i] = 0.f; }
  if (i < 2) scal[i] = 0.f;
  if (i < PAD_SLOTS) { wgt_slot[i] = 0.f; tok_slot[i] = 0; }
  if (i < SCHED_MAX) sched_e[i] = -1;
}

// ---------------- router logits GEMM: lp[kc][t][e] partial sums ----------------
__global__ __launch_bounds__(256) void k_logits(const float* __restrict__ x,
                                                const float* __restrict__ rw,
                                                float* __restrict__ lp) {
  __shared__ float rw_s[8][256];
  int tid = threadIdx.x;
  int tg = blockIdx.x, eg = blockIdx.y, kc = blockIdx.z;
  #pragma unroll
  for (int idx = 0; idx < 8; idx++)
    rw_s[idx][tid] = rw[(size_t)(eg*8 + idx)*D_EMBD + kc*256 + tid];
  __syncthreads();
  int tok = tg*256 + tid;
  const float4* x4 = reinterpret_cast<const float4*>(x + (size_t)tok*D_EMBD + kc*256);
  float acc[8];
  #pragma unroll
  for (int e = 0; e < 8; e++) acc[e] = 0.f;
  #pragma unroll 4
  for (int k4 = 0; k4 < 64; k4++) {
    float4 xv = x4[k4];
    #pragma unroll
    for (int e = 0; e < 8; e++)
      acc[e] += xv.x*rw_s[e][k4*4+0] + xv.y*rw_s[e][k4*4+1]
              + xv.z*rw_s[e][k4*4+2] + xv.w*rw_s[e][k4*4+3];
  }
  float* dst = lp + (size_t)kc*T_TOKENS*N_EXP + (size_t)tok*N_EXP + eg*8;
  float4 o0 = {acc[0], acc[1], acc[2], acc[3]};
  float4 o1 = {acc[4], acc[5], acc[6], acc[7]};
  reinterpret_cast<float4*>(dst)[0] = o0;
  reinterpret_cast<float4*>(dst)[1] = o1;
}

// ---------------- router part 2: sigmoid, parallel-rank top-8, losses ----------------
__global__ __launch_bounds__(256) void k_router2(const float* __restrict__ lp,
                          int* __restrict__ sel_e, float* __restrict__ sel_w,
                          int* __restrict__ counts, float* __restrict__ psum,
                          float* __restrict__ scal) {
  __shared__ float psum_s[4][64];
  __shared__ int cnt_s[4][64];
  int tid = threadIdx.x, wv = tid >> 6, lane = tid & 63;
  float pacc = 0.f, zacc = 0.f;
  int cacc = 0;
  int tbase = blockIdx.x*8 + wv*2;
  #pragma unroll
  for (int it = 0; it < 2; it++) {
    int t = tbase + it;
    float logit = lp[(size_t)t*N_EXP + lane]
                + lp[(size_t)T_TOKENS*N_EXP + (size_t)t*N_EXP + lane]
                + lp[2*(size_t)T_TOKENS*N_EXP + (size_t)t*N_EXP + lane];
    float prob = 1.f/(1.f + expf(-logit));
    pacc += prob;
    float mx = logit;
    for (int s = 32; s; s >>= 1) mx = fmaxf(mx, __shfl_xor(mx, s, 64));
    float sse = expf(logit - mx);
    for (int s = 32; s; s >>= 1) sse += __shfl_xor(sse, s, 64);
    float lse = mx + logf(sse);
    zacc += lse*lse;
    int rank = 0;
    #pragma unroll
    for (int j = 0; j < 64; j++) {
      float pj = __shfl(prob, j, 64);
      rank += (pj > prob || (pj == prob && j < lane)) ? 1 : 0;
    }
    bool sel = rank < TOPK;
    float sp = sel ? prob : 0.f;
    for (int s = 32; s; s >>= 1) sp += __shfl_xor(sp, s, 64);
    if (sel) {
      sel_e[t*TOPK + rank] = lane;
      sel_w[t*TOPK + rank] = prob / (sp + 1e-20f);
      cacc++;
    }
  }
  psum_s[wv][lane] = pacc;
  cnt_s[wv][lane] = cacc;
  if (lane == 0) atomicAdd(&scal[0], zacc);
  __syncthreads();
  if (tid < 64) {
    float p = psum_s[0][tid] + psum_s[1][tid] + psum_s[2][tid] + psum_s[3][tid];
    int c = cnt_s[0][tid] + cnt_s[1][tid] + cnt_s[2][tid] + cnt_s[3][tid];
    atomicAdd(&psum[tid], p);
    atomicAdd(&counts[tid], c);
  }
}

// ---------------- schedule: 64-row tiles, XCD-grouped positions ----------------
__global__ void k_schedule(const int* __restrict__ counts, int* __restrict__ offsets,
                           int* __restrict__ sched_e, int* __restrict__ sched_r0) {
  int e = threadIdx.x;   // 64 threads, one wave
  int c = counts[e];
  int tiles = (c + 63) >> 6;
  int padded = tiles << 6;
  int ip = padded;
  for (int s = 1; s < 64; s <<= 1) { int v = __shfl_up(ip, s, 64); if (e >= s) ip += v; }
  int rowoff = ip - padded;
  offsets[e] = rowoff;
  int it = tiles;
  for (int s = 8; s < 64; s <<= 1) { int v = __shfl_up(it, s, 64); if (e >= s) it += v; }
  int rank = it - tiles;
  int xcd = e & 7;
  for (int i = 0; i < tiles; i++) {
    int p = xcd + 8*(rank + i);
    sched_e[p] = e;
    sched_r0[p] = rowoff + i*64;
  }
}

// ---------------- assign tokens to slots ----------------
__global__ void k_assign(const int* __restrict__ sel_e, const float* __restrict__ sel_w,
                         const int* __restrict__ offsets, int* __restrict__ cursor,
                         int* __restrict__ tok_slot, float* __restrict__ wgt_slot,
                         int* __restrict__ slot_tk) {
  int i = blockIdx.x*256 + threadIdx.x;   // 16384
  int e = sel_e[i];
  int pos = atomicAdd(&cursor[e], 1);
  int slot = offsets[e] + pos;
  tok_slot[slot] = i >> 3;
  wgt_slot[slot] = sel_w[i];
  slot_tk[i] = slot;
}

// ---------------- FUSED MoE MLP: per 64-row expert tile, h kept in LDS ----------------
// Phase A (x@W1 -> relu^2*gate -> Hs): 2 passes of 128 cols, 12 K-steps each,
//   exact round-12 fused fp32 staging (A = x fp32 gathered, B = w1 fp32 native).
// Phase B (Hs@W2 -> yprm): 6 nch of 128 cols, 4 K-steps each, B = w2 fp32 native,
//   A fragments read straight from Hs (chunk-XOR swizzle matches write side).
__global__ __launch_bounds__(256) void k_moe_mlp(
    const float* __restrict__ x, const float* __restrict__ w1,
    const float* __restrict__ w2,
    const int* __restrict__ sched_e, const int* __restrict__ sched_r0,
    const int* __restrict__ tok_slot, const float* __restrict__ wgt_slot,
    __hip_bfloat16* __restrict__ yprm) {
  __shared__ __hip_bfloat16 As[2][64*64];    // 8 KB x2
  __shared__ __hip_bfloat16 Bs[2][128*64];   // 16 KB x2
  __shared__ __hip_bfloat16 Hs[64*256];      // 32 KB  (h tile, swizzled)
  int tid = threadIdx.x;
  int n4 = tid & 31, kpb = tid >> 5;         // B staging: col-quad, k-octet
  int mrow = tid >> 4, k4f = tid & 15;       // A staging (phase A)
  int wv = tid >> 6, lane = tid & 63;
  int wm = wv >> 1, wn = wv & 1;
  int l15 = lane & 15, l4 = lane >> 4;

  for (int p = blockIdx.x; p < SCHED_MAX; p += gridDim.x) {
    int e = sched_e[p];
    if (e < 0) continue;
    int r0 = sched_r0[p];

    int tks[4];
    #pragma unroll
    for (int i = 0; i < 4; i++) tks[i] = tok_slot[r0 + i*16 + mrow];

    // mutable B-source params (set per pass)
    const float* bsrc = w1;
    int bstr = TW;
    size_t browb = 0;
    int bcolb = 0;

    float bv[8][4], av[4][4];
    f32x4 acc[2][4];
    f32x4 z = {0.f, 0.f, 0.f, 0.f};

    auto B_LD = [&](int k0) {
      const float* rp = bsrc + (browb + (size_t)(k0 + kpb*8))*bstr + bcolb + n4*4;
      #pragma unroll
      for (int r = 0; r < 8; r++)
        *reinterpret_cast<float4*>(&bv[r][0]) =
            *reinterpret_cast<const float4*>(rp + (size_t)r*bstr);
    };
    auto B_WR = [&](int bsel) {
      char* bs = (char*)&Bs[bsel][0];
      #pragma unroll
      for (int c = 0; c < 4; c++) {
        int n = n4*4 + c;
        int ch = kpb ^ ((n & 7) ^ ((n >> 3) & 7));
        uint4 o = { pk2(bv[0][c], bv[1][c]), pk2(bv[2][c], bv[3][c]),
                    pk2(bv[4][c], bv[5][c]), pk2(bv[6][c], bv[7][c]) };
        *reinterpret_cast<uint4*>(bs + n*128 + ch*16) = o;
      }
    };
    auto A_LD = [&](int k0) {
      #pragma unroll
      for (int i = 0; i < 4; i++)
        *reinterpret_cast<float4*>(&av[i][0]) =
            *reinterpret_cast<const float4*>(x + (size_t)tks[i]*D_EMBD + k0 + k4f*4);
    };
    auto A_WR = [&](int bsel) {
      char* as_ = (char*)&As[bsel][0];
      #pragma unroll
      for (int i = 0; i < 4; i++) {
        int m = i*16 + mrow;
        int ch = (k4f >> 1) ^ (m & 7);
        uint2 val = { pk2(av[i][0], av[i][1]), pk2(av[i][2], av[i][3]) };
        *reinterpret_cast<uint2*>(as_ + m*128 + ch*16 + (k4f & 1)*8) = val;
      }
    };
    auto ZERO = [&]() {
      #pragma unroll
      for (int m = 0; m < 2; m++)
        #pragma unroll
        for (int n = 0; n < 4; n++) acc[m][n] = z;
    };
    auto MFMA_AB = [&](bf16x8 (&af)[2][2], const char* bsC) {
      bf16x8 bq[4][2];
      #pragma unroll
      for (int n = 0; n < 4; n++) {
        int rb = wn*64 + n*16 + l15;
        int Sb = (rb & 7) ^ ((rb >> 3) & 7);
        #pragma unroll
        for (int kk = 0; kk < 2; kk++)
          bq[n][kk] = *reinterpret_cast<const bf16x8*>(
              bsC + rb*128 + (((kk*4 + l4) ^ Sb) << 4));
      }
      #pragma unroll
      for (int kk = 0; kk < 2; kk++)
        #pragma unroll
        for (int m = 0; m < 2; m++)
          #pragma unroll
          for (int n = 0; n < 4; n++)
            acc[m][n] = __builtin_amdgcn_mfma_f32_16x16x32_bf16(af[m][kk], bq[n][kk], acc[m][n], 0, 0, 0);
    };

    // ================= Phase A: h = relu(x @ W1_e)^2 * gate -> Hs =================
    #pragma unroll 1
    for (int nch1 = 0; nch1 < 2; nch1++) {
      bsrc = w1; bstr = TW; browb = 0; bcolb = e*EW + nch1*128;
      ZERO();
      A_LD(0); B_LD(0); A_WR(0); B_WR(0);
      __syncthreads();
      int cur = 0;
      for (int step = 0; step < 12; step++) {
        bool more = (step + 1 < 12);
        if (more) { A_LD((step + 1)*64); B_LD((step + 1)*64); }
        const char* asC = (const char*)&As[cur][0];
        bf16x8 af[2][2];
        #pragma unroll
        for (int m = 0; m < 2; m++) {
          int ra = wm*32 + m*16 + l15;
          #pragma unroll
          for (int kk = 0; kk < 2; kk++)
            af[m][kk] = *reinterpret_cast<const bf16x8*>(
                asC + ra*128 + (((kk*4 + l4) ^ (ra & 7)) << 4));
        }
        MFMA_AB(af, (const char*)&Bs[cur][0]);
        if (more) { A_WR(cur ^ 1); B_WR(cur ^ 1); }
        __syncthreads();
        cur ^= 1;
      }
      // epilogue -> Hs (chunk-XOR swizzled: g=col>>3, ch=(g&~7)|((g&7)^(row&7)))
      char* hsC = (char*)&Hs[0];
      #pragma unroll
      for (int m = 0; m < 2; m++)
        #pragma unroll
        for (int j = 0; j < 4; j++) {
          int row = wm*32 + m*16 + l4*4 + j;
          float wg = wgt_slot[r0 + row];
          #pragma unroll
          for (int n = 0; n < 4; n++) {
            int col = nch1*128 + wn*64 + n*16 + l15;
            float v = fmaxf(acc[m][n][j], 0.f);
            int g = col >> 3;
            int ch = (g & ~7) | ((g & 7) ^ (row & 7));
            *reinterpret_cast<unsigned short*>(hsC + row*512 + ch*16 + (col & 7)*2)
                = f2bu(v*v*wg);
          }
        }
    }
    __syncthreads();

    // ================= Phase B: y = Hs @ W2_e -> yprm =================
    const char* hsC = (const char*)&Hs[0];
    #pragma unroll 1
    for (int nch = 0; nch < 6; nch++) {
      bsrc = w2; bstr = D_EMBD; browb = (size_t)e*EW; bcolb = nch*128;
      ZERO();
      B_LD(0); B_WR(0);
      __syncthreads();
      int cur = 0;
      for (int step = 0; step < 4; step++) {
        bool more = (step + 1 < 4);
        if (more) B_LD((step + 1)*64);
        bf16x8 af[2][2];
        #pragma unroll
        for (int m = 0; m < 2; m++) {
          int ra = wm*32 + m*16 + l15;
          #pragma unroll
          for (int kk = 0; kk < 2; kk++) {
            int g = step*8 + kk*4 + l4;
            int ch = (g & ~7) | ((g & 7) ^ (ra & 7));
            af[m][kk] = *reinterpret_cast<const bf16x8*>(hsC + ra*512 + ch*16);
          }
        }
        MFMA_AB(af, (const char*)&Bs[cur][0]);
        if (more) B_WR(cur ^ 1);
        __syncthreads();
        cur ^= 1;
      }
      #pragma unroll
      for (int m = 0; m < 2; m++)
        #pragma unroll
        for (int j = 0; j < 4; j++) {
          int r = r0 + wm*32 + m*16 + l4*4 + j;
          #pragma unroll
          for (int n = 0; n < 4; n++) {
            int col = nch*128 + wn*64 + n*16 + l15;
            yprm[(size_t)r*D_EMBD + col] = __float2bfloat16(acc[m][n][j]);
          }
        }
    }
    __syncthreads();   // Hs/As/Bs reuse guard for next tile
  }
}

// ---------------- combine 8 expert rows per token (vectorized gather) ----------------
__global__ void k_combine(const __hip_bfloat16* __restrict__ y, const int* __restrict__ slot_tk,
                          float* __restrict__ out) {
  __shared__ int s[TOPK];
  int t = blockIdx.x, tid = threadIdx.x;
  if (tid < TOPK) s[tid] = slot_tk[t*TOPK + tid];
  __syncthreads();
  if (tid < 192) {
    int c = tid*4;
    float a0 = 0.f, a1 = 0.f, a2 = 0.f, a3 = 0.f;
    #pragma unroll
    for (int k = 0; k < TOPK; k++) {
      ushort4 v = *reinterpret_cast<const ushort4*>(&y[(size_t)s[k]*D_EMBD + c]);
      union { unsigned int u; float f; } f0, f1, f2, f3;
      f0.u = ((unsigned int)v.x) << 16;
      f1.u = ((unsigned int)v.y) << 16;
      f2.u = ((unsigned int)v.z) << 16;
      f3.u = ((unsigned int)v.w) << 16;
      a0 += f0.f; a1 += f1.f; a2 += f2.f; a3 += f3.f;
    }
    float4 o = {a0, a1, a2, a3};
    *reinterpret_cast<float4*>(&out[(size_t)t*D_EMBD + c]) = o;
  }
}

// ---------------- aux losses + f_i ----------------
__global__ void k_finalize(const int* __restrict__ counts, const float* __restrict__ psum,
                           const float* __restrict__ scal, float* __restrict__ out) {
  __shared__ float part[N_EXP], ptot[N_EXP];
  int e = threadIdx.x;
  float f = (float)counts[e] / 16384.f;
  float p = psum[e] / 2048.f;
  part[e] = f * p;
  ptot[e] = p;
  out[OUT_BASE + 3 + e] = f;
  __syncthreads();
  if (e == 0) {
    float s = 0.f, q = 0.f;
    for (int i = 0; i < N_EXP; i++) { s += part[i]; q += ptot[i]; }
    out[OUT_BASE + 0] = scal[0] / 2048.f;      // router_z_loss
    out[OUT_BASE + 1] = 64.f * s;              // load_balance_loss
    out[OUT_BASE + 2] = q;                     // compute_loss
  }
}

extern "C" void kernel_launch(void* const* d_in, const int* in_sizes, int n_in,
                              void* d_out, int out_size, void* d_ws, size_t ws_size,
                              hipStream_t stream) {
  const float* x  = (const float*)d_in[0];
  const float* rw = (const float*)d_in[1];
  const float* w1 = (const float*)d_in[2];
  const float* w2 = (const float*)d_in[3];
  float* out = (float*)d_out;
  char* ws = (char*)d_ws;

  size_t o = 0;
  auto alloc = [&](size_t b) { size_t r = o; o += (b + 255) & ~(size_t)255; return r; };
  __hip_bfloat16* yprm  = (__hip_bfloat16*)(ws + alloc((size_t)PAD_SLOTS*768*2));
  float* lp      = (float*)(ws + alloc(3UL*2048*64*4));
  int*   sel_e   = (int*)  (ws + alloc(16384UL*4));
  float* sel_w   = (float*)(ws + alloc(16384UL*4));
  int*   slot_tk = (int*)  (ws + alloc(16384UL*4));
  int*   tokslot = (int*)  (ws + alloc((size_t)PAD_SLOTS*4));
  float* wgtslot = (float*)(ws + alloc((size_t)PAD_SLOTS*4));
  int*   counts  = (int*)  (ws + alloc(256));
  int*   cursor  = (int*)  (ws + alloc(256));
  float* psum    = (float*)(ws + alloc(256));
  float* scal    = (float*)(ws + alloc(256));
  int*   offsets = (int*)  (ws + alloc(256));
  int*   sch_e   = (int*)  (ws + alloc(SCHED_MAX*4));
  int*   sch_r0  = (int*)  (ws + alloc(SCHED_MAX*4));

  k_init<<<80, 256, 0, stream>>>(counts, cursor, psum, scal, wgtslot, tokslot, sch_e);
  k_logits<<<dim3(8, 8, 3), 256, 0, stream>>>(x, rw, lp);
  k_router2<<<256, 256, 0, stream>>>(lp, sel_e, sel_w, counts, psum, scal);
  k_schedule<<<1, 64, 0, stream>>>(counts, offsets, sch_e, sch_r0);
  k_assign<<<64, 256, 0, stream>>>(sel_e, sel_w, offsets, cursor, tokslot, wgtslot, slot_tk);
  k_moe_mlp<<<512, 256, 0, stream>>>(x, w1, w2, sch_e, sch_r0, tokslot, wgtslot, yprm);
  k_combine<<<2048, 256, 0, stream>>>(yprm, slot_tk, out);
  k_finalize<<<1, 64, 0, stream>>>(counts, psum, scal, out);
}

// Round 18
// 149.437 us; speedup vs baseline: 1.1019x; 1.0178x over previous
//
#include <hip/hip_runtime.h>
#include <hip/hip_bf16.h>

#define T_TOKENS 2048
#define D_EMBD 768
#define N_EXP 64
#define EW 256
#define TOPK 8
#define TW (N_EXP*EW)
#define PAD_SLOTS 20480   // 16384 + 64*63 rounded up to 64-tile granularity
#define SCHED_MAX 2560    // 8 * 320 XCD-grouped positions
#define OUT_BASE (2048*768)

typedef __attribute__((ext_vector_type(8))) short bf16x8;
typedef __attribute__((ext_vector_type(4))) float f32x4;

__device__ inline unsigned short f2bu(float f) {
  union { __hip_bfloat16 b; unsigned short u; } cv; cv.b = __float2bfloat16(f); return cv.u;
}
__device__ inline unsigned int pk2(float a, float b) {
  return (unsigned int)f2bu(a) | ((unsigned int)f2bu(b) << 16);
}

// ---------------- init ----------------
__global__ void k_init(int* counts, int* cursor, float* psum, float* scal,
                       float* wgt_slot, int* tok_slot, int* sched_e) {
  int i = blockIdx.x*256 + threadIdx.x;   // 20480 threads
  if (i < N_EXP) { counts[i] = 0; cursor[i] = 0; psum[i] = 0.f; }
  if (i < 2) scal[i] = 0.f;
  if (i < PAD_SLOTS) { wgt_slot[i] = 0.f; tok_slot[i] = 0; }
  if (i < SCHED_MAX) sched_e[i] = -1;
}

// ---------------- router logits GEMM: lp[kc][t][e] partial sums ----------------
__global__ __launch_bounds__(256) void k_logits(const float* __restrict__ x,
                                                const float* __restrict__ rw,
                                                float* __restrict__ lp) {
  __shared__ float rw_s[8][256];
  int tid = threadIdx.x;
  int tg = blockIdx.x, eg = blockIdx.y, kc = blockIdx.z;
  #pragma unroll
  for (int idx = 0; idx < 8; idx++)
    rw_s[idx][tid] = rw[(size_t)(eg*8 + idx)*D_EMBD + kc*256 + tid];
  __syncthreads();
  int tok = tg*256 + tid;
  const float4* x4 = reinterpret_cast<const float4*>(x + (size_t)tok*D_EMBD + kc*256);
  float acc[8];
  #pragma unroll
  for (int e = 0; e < 8; e++) acc[e] = 0.f;
  #pragma unroll 4
  for (int k4 = 0; k4 < 64; k4++) {
    float4 xv = x4[k4];
    #pragma unroll
    for (int e = 0; e < 8; e++)
      acc[e] += xv.x*rw_s[e][k4*4+0] + xv.y*rw_s[e][k4*4+1]
              + xv.z*rw_s[e][k4*4+2] + xv.w*rw_s[e][k4*4+3];
  }
  float* dst = lp + (size_t)kc*T_TOKENS*N_EXP + (size_t)tok*N_EXP + eg*8;
  float4 o0 = {acc[0], acc[1], acc[2], acc[3]};
  float4 o1 = {acc[4], acc[5], acc[6], acc[7]};
  reinterpret_cast<float4*>(dst)[0] = o0;
  reinterpret_cast<float4*>(dst)[1] = o1;
}

// ---------------- router part 2: sigmoid, parallel-rank top-8, losses ----------------
__global__ __launch_bounds__(256) void k_router2(const float* __restrict__ lp,
                          int* __restrict__ sel_e, float* __restrict__ sel_w,
                          int* __restrict__ counts, float* __restrict__ psum,
                          float* __restrict__ scal) {
  __shared__ float psum_s[4][64];
  __shared__ int cnt_s[4][64];
  int tid = threadIdx.x, wv = tid >> 6, lane = tid & 63;
  float pacc = 0.f, zacc = 0.f;
  int cacc = 0;
  int tbase = blockIdx.x*8 + wv*2;
  #pragma unroll
  for (int it = 0; it < 2; it++) {
    int t = tbase + it;
    float logit = lp[(size_t)t*N_EXP + lane]
                + lp[(size_t)T_TOKENS*N_EXP + (size_t)t*N_EXP + lane]
                + lp[2*(size_t)T_TOKENS*N_EXP + (size_t)t*N_EXP + lane];
    float prob = 1.f/(1.f + expf(-logit));
    pacc += prob;
    float mx = logit;
    for (int s = 32; s; s >>= 1) mx = fmaxf(mx, __shfl_xor(mx, s, 64));
    float sse = expf(logit - mx);
    for (int s = 32; s; s >>= 1) sse += __shfl_xor(sse, s, 64);
    float lse = mx + logf(sse);
    zacc += lse*lse;
    int rank = 0;
    #pragma unroll
    for (int j = 0; j < 64; j++) {
      float pj = __shfl(prob, j, 64);
      rank += (pj > prob || (pj == prob && j < lane)) ? 1 : 0;
    }
    bool sel = rank < TOPK;
    float sp = sel ? prob : 0.f;
    for (int s = 32; s; s >>= 1) sp += __shfl_xor(sp, s, 64);
    if (sel) {
      sel_e[t*TOPK + rank] = lane;
      sel_w[t*TOPK + rank] = prob / (sp + 1e-20f);
      cacc++;
    }
  }
  psum_s[wv][lane] = pacc;
  cnt_s[wv][lane] = cacc;
  if (lane == 0) atomicAdd(&scal[0], zacc);
  __syncthreads();
  if (tid < 64) {
    float p = psum_s[0][tid] + psum_s[1][tid] + psum_s[2][tid] + psum_s[3][tid];
    int c = cnt_s[0][tid] + cnt_s[1][tid] + cnt_s[2][tid] + cnt_s[3][tid];
    atomicAdd(&psum[tid], p);
    atomicAdd(&counts[tid], c);
  }
}

// ---------------- schedule: 64-row tiles, XCD-grouped positions ----------------
__global__ void k_schedule(const int* __restrict__ counts, int* __restrict__ offsets,
                           int* __restrict__ sched_e, int* __restrict__ sched_r0) {
  int e = threadIdx.x;   // 64 threads, one wave
  int c = counts[e];
  int tiles = (c + 63) >> 6;
  int padded = tiles << 6;
  int ip = padded;
  for (int s = 1; s < 64; s <<= 1) { int v = __shfl_up(ip, s, 64); if (e >= s) ip += v; }
  int rowoff = ip - padded;
  offsets[e] = rowoff;
  int it = tiles;
  for (int s = 8; s < 64; s <<= 1) { int v = __shfl_up(it, s, 64); if (e >= s) it += v; }
  int rank = it - tiles;
  int xcd = e & 7;
  for (int i = 0; i < tiles; i++) {
    int p = xcd + 8*(rank + i);
    sched_e[p] = e;
    sched_r0[p] = rowoff + i*64;
  }
}

// ---------------- assign tokens to slots ----------------
__global__ void k_assign(const int* __restrict__ sel_e, const float* __restrict__ sel_w,
                         const int* __restrict__ offsets, int* __restrict__ cursor,
                         int* __restrict__ tok_slot, float* __restrict__ wgt_slot,
                         int* __restrict__ slot_tk) {
  int i = blockIdx.x*256 + threadIdx.x;   // 16384
  int e = sel_e[i];
  int pos = atomicAdd(&cursor[e], 1);
  int slot = offsets[e] + pos;
  tok_slot[slot] = i >> 3;
  wgt_slot[slot] = sel_w[i];
  slot_tk[i] = slot;
}

// ---------------- grouped GEMM: 64x256 tile, BK=64, 512 threads, fused fp32 staging ----
// Full-expert-width N-tile: B reads are 1KB islands (vs 512B) and each expert's W1
// panel is staged exactly ONCE (W2: 3x instead of 6x).
// MODE 1: A = x fp32 (gathered rows, reg-cvt), B = w1 fp32 native; grid (512, 1)
// MODE 2: A = hprm bf16 (reg-staged),         B = w2 fp32 native; grid (512, 3)
template<int MODE>
__global__ __launch_bounds__(512) void k_moe_gemm(
    const void* __restrict__ Asrc, const float* __restrict__ Bsrc,
    const int* __restrict__ sched_e, const int* __restrict__ sched_r0,
    const int* __restrict__ tok_slot, const float* __restrict__ wgt_slot,
    __hip_bfloat16* __restrict__ outp) {
  constexpr int NS   = (MODE == 1) ? 12 : 4;
  constexpr int BSTR = (MODE == 1) ? TW : D_EMBD;
  __shared__ __hip_bfloat16 As[2][64*64];    // 8 KB x2
  __shared__ __hip_bfloat16 Bs[2][256*64];   // 32 KB x2
  int tid = threadIdx.x;
  int nch = blockIdx.y;
  int n4 = tid & 63, kpb = tid >> 6;         // B staging: col-quad (0..63), k-octet (0..7)
  int arow = tid >> 3, akc = tid & 7;        // A staging: row (0..63), k-octet (0..7)
  int wv = tid >> 6, lane = tid & 63;
  int wm = wv >> 1, wn = wv & 1;             // 4 m-groups x 2 n-halves
  int l15 = lane & 15, l4 = lane >> 4;

  for (int p = blockIdx.x; p < SCHED_MAX; p += gridDim.x) {
    int e = sched_e[p];
    if (e < 0) continue;
    int r0 = sched_r0[p];

    size_t browb = (MODE == 1) ? 0 : (size_t)e*EW;         // B k-row base
    int bcolb = (MODE == 1) ? e*EW : nch*EW;               // B col base (full 256)

    int tok = 0;
    size_t a_base = 0;
    if (MODE == 1) tok = tok_slot[r0 + arow];
    else           a_base = (size_t)(r0 + arow) * EW;

    float bv[8][4];
    float av[8];
    uint4 au;

    auto B_LD = [&](int k0) {
      const float* rp = Bsrc + (browb + (size_t)(k0 + kpb*8))*BSTR + bcolb + n4*4;
      #pragma unroll
      for (int r = 0; r < 8; r++)
        *reinterpret_cast<float4*>(&bv[r][0]) =
            *reinterpret_cast<const float4*>(rp + (size_t)r*BSTR);
    };
    auto B_WR = [&](int bsel) {
      char* bs = (char*)&Bs[bsel][0];
      #pragma unroll
      for (int c = 0; c < 4; c++) {
        int n = n4*4 + c;
        int ch = kpb ^ ((n & 7) ^ ((n >> 3) & 7));
        uint4 o = { pk2(bv[0][c], bv[1][c]), pk2(bv[2][c], bv[3][c]),
                    pk2(bv[4][c], bv[5][c]), pk2(bv[6][c], bv[7][c]) };
        *reinterpret_cast<uint4*>(bs + n*128 + ch*16) = o;
      }
    };
    auto A_LD1 = [&](int k0) {
      const float* xf = (const float*)Asrc;
      const float4* rp = reinterpret_cast<const float4*>(xf + (size_t)tok*D_EMBD + k0 + akc*8);
      *reinterpret_cast<float4*>(&av[0]) = rp[0];
      *reinterpret_cast<float4*>(&av[4]) = rp[1];
    };
    auto A_WR1 = [&](int bsel) {
      char* as_ = (char*)&As[bsel][0];
      int ch = akc ^ (arow & 7);
      uint4 o = { pk2(av[0], av[1]), pk2(av[2], av[3]),
                  pk2(av[4], av[5]), pk2(av[6], av[7]) };
      *reinterpret_cast<uint4*>(as_ + arow*128 + ch*16) = o;
    };
    auto A_LD2 = [&](int k0) {
      const __hip_bfloat16* hb = (const __hip_bfloat16*)Asrc;
      au = *reinterpret_cast<const uint4*>(hb + a_base + k0 + (akc ^ (arow & 7))*8);
    };
    auto A_WR2 = [&](int bsel) {
      char* as_ = (char*)&As[bsel][0];
      *reinterpret_cast<uint4*>(as_ + arow*128 + (akc ^ (arow & 7))*16) = au;
    };

    f32x4 acc[8];
    f32x4 z = {0.f, 0.f, 0.f, 0.f};
    #pragma unroll
    for (int n = 0; n < 8; n++) acc[n] = z;

    auto COMPUTE = [&](int bsel) {
      const char* asC = (const char*)&As[bsel][0];
      const char* bsC = (const char*)&Bs[bsel][0];
      int ra = wm*16 + l15;
      bf16x8 af0 = *reinterpret_cast<const bf16x8*>(
          asC + ra*128 + (((0*4 + l4) ^ (ra & 7)) << 4));
      bf16x8 af1 = *reinterpret_cast<const bf16x8*>(
          asC + ra*128 + (((1*4 + l4) ^ (ra & 7)) << 4));
      #pragma unroll
      for (int n = 0; n < 8; n++) {
        int rb = wn*128 + n*16 + l15;
        int Sb = (rb & 7) ^ ((rb >> 3) & 7);
        bf16x8 b0 = *reinterpret_cast<const bf16x8*>(
            bsC + rb*128 + (((0*4 + l4) ^ Sb) << 4));
        bf16x8 b1 = *reinterpret_cast<const bf16x8*>(
            bsC + rb*128 + (((1*4 + l4) ^ Sb) << 4));
        acc[n] = __builtin_amdgcn_mfma_f32_16x16x32_bf16(af0, b0, acc[n], 0, 0, 0);
        acc[n] = __builtin_amdgcn_mfma_f32_16x16x32_bf16(af1, b1, acc[n], 0, 0, 0);
      }
    };

    // prologue: stage step 0 into buf 0
    if (MODE == 1) { A_LD1(0); B_LD(0); A_WR1(0); B_WR(0); }
    else           { A_LD2(0); B_LD(0); A_WR2(0); B_WR(0); }
    __syncthreads();

    int cur = 0;
    for (int step = 0; step < NS; step++) {
      bool more = (step + 1 < NS);
      int k1 = (step + 1)*64;
      if (more) {
        if (MODE == 1) { A_LD1(k1); B_LD(k1); }
        else           { A_LD2(k1); B_LD(k1); }
      }
      COMPUTE(cur);
      if (more) {
        if (MODE == 1) { A_WR1(cur ^ 1); B_WR(cur ^ 1); }
        else           { A_WR2(cur ^ 1); B_WR(cur ^ 1); }
      }
      __syncthreads();
      cur ^= 1;
    }

    if (MODE == 1) {
      #pragma unroll
      for (int j = 0; j < 4; j++) {
        int r = r0 + wm*16 + l4*4 + j;
        float wg = wgt_slot[r];
        #pragma unroll
        for (int n = 0; n < 8; n++) {
          int col = wn*128 + n*16 + l15;
          float v = fmaxf(acc[n][j], 0.f);
          outp[(size_t)r*EW + col] = __float2bfloat16(v*v*wg);
        }
      }
    } else {
      #pragma unroll
      for (int j = 0; j < 4; j++) {
        int r = r0 + wm*16 + l4*4 + j;
        #pragma unroll
        for (int n = 0; n < 8; n++) {
          int col = nch*EW + wn*128 + n*16 + l15;
          outp[(size_t)r*D_EMBD + col] = __float2bfloat16(acc[n][j]);
        }
      }
    }
  }
}

// ---------------- combine 8 expert rows per token (vectorized gather) ----------------
__global__ void k_combine(const __hip_bfloat16* __restrict__ y, const int* __restrict__ slot_tk,
                          float* __restrict__ out) {
  __shared__ int s[TOPK];
  int t = blockIdx.x, tid = threadIdx.x;
  if (tid < TOPK) s[tid] = slot_tk[t*TOPK + tid];
  __syncthreads();
  if (tid < 192) {
    int c = tid*4;
    float a0 = 0.f, a1 = 0.f, a2 = 0.f, a3 = 0.f;
    #pragma unroll
    for (int k = 0; k < TOPK; k++) {
      ushort4 v = *reinterpret_cast<const ushort4*>(&y[(size_t)s[k]*D_EMBD + c]);
      union { unsigned int u; float f; } f0, f1, f2, f3;
      f0.u = ((unsigned int)v.x) << 16;
      f1.u = ((unsigned int)v.y) << 16;
      f2.u = ((unsigned int)v.z) << 16;
      f3.u = ((unsigned int)v.w) << 16;
      a0 += f0.f; a1 += f1.f; a2 += f2.f; a3 += f3.f;
    }
    float4 o = {a0, a1, a2, a3};
    *reinterpret_cast<float4*>(&out[(size_t)t*D_EMBD + c]) = o;
  }
}

// ---------------- aux losses + f_i ----------------
__global__ void k_finalize(const int* __restrict__ counts, const float* __restrict__ psum,
                           const float* __restrict__ scal, float* __restrict__ out) {
  __shared__ float part[N_EXP], ptot[N_EXP];
  int e = threadIdx.x;
  float f = (float)counts[e] / 16384.f;
  float p = psum[e] / 2048.f;
  part[e] = f * p;
  ptot[e] = p;
  out[OUT_BASE + 3 + e] = f;
  __syncthreads();
  if (e == 0) {
    float s = 0.f, q = 0.f;
    for (int i = 0; i < N_EXP; i++) { s += part[i]; q += ptot[i]; }
    out[OUT_BASE + 0] = scal[0] / 2048.f;      // router_z_loss
    out[OUT_BASE + 1] = 64.f * s;              // load_balance_loss
    out[OUT_BASE + 2] = q;                     // compute_loss
  }
}

extern "C" void kernel_launch(void* const* d_in, const int* in_sizes, int n_in,
                              void* d_out, int out_size, void* d_ws, size_t ws_size,
                              hipStream_t stream) {
  const float* x  = (const float*)d_in[0];
  const float* rw = (const float*)d_in[1];
  const float* w1 = (const float*)d_in[2];
  const float* w2 = (const float*)d_in[3];
  float* out = (float*)d_out;
  char* ws = (char*)d_ws;

  size_t o = 0;
  auto alloc = [&](size_t b) { size_t r = o; o += (b + 255) & ~(size_t)255; return r; };
  __hip_bfloat16* hprm  = (__hip_bfloat16*)(ws + alloc((size_t)PAD_SLOTS*256*2));
  __hip_bfloat16* yprm  = (__hip_bfloat16*)(ws + alloc((size_t)PAD_SLOTS*768*2));
  float* lp      = (float*)(ws + alloc(3UL*2048*64*4));
  int*   sel_e   = (int*)  (ws + alloc(16384UL*4));
  float* sel_w   = (float*)(ws + alloc(16384UL*4));
  int*   slot_tk = (int*)  (ws + alloc(16384UL*4));
  int*   tokslot = (int*)  (ws + alloc((size_t)PAD_SLOTS*4));
  float* wgtslot = (float*)(ws + alloc((size_t)PAD_SLOTS*4));
  int*   counts  = (int*)  (ws + alloc(256));
  int*   cursor  = (int*)  (ws + alloc(256));
  float* psum    = (float*)(ws + alloc(256));
  float* scal    = (float*)(ws + alloc(256));
  int*   offsets = (int*)  (ws + alloc(256));
  int*   sch_e   = (int*)  (ws + alloc(SCHED_MAX*4));
  int*   sch_r0  = (int*)  (ws + alloc(SCHED_MAX*4));

  k_init<<<80, 256, 0, stream>>>(counts, cursor, psum, scal, wgtslot, tokslot, sch_e);
  k_logits<<<dim3(8, 8, 3), 256, 0, stream>>>(x, rw, lp);
  k_router2<<<256, 256, 0, stream>>>(lp, sel_e, sel_w, counts, psum, scal);
  k_schedule<<<1, 64, 0, stream>>>(counts, offsets, sch_e, sch_r0);
  k_assign<<<64, 256, 0, stream>>>(sel_e, sel_w, offsets, cursor, tokslot, wgtslot, slot_tk);
  k_moe_gemm<1><<<dim3(512, 1), 512, 0, stream>>>((const void*)x, w1, sch_e, sch_r0, tokslot, wgtslot, hprm);
  k_moe_gemm<2><<<dim3(512, 3), 512, 0, stream>>>((const void*)hprm, w2, sch_e, sch_r0, tokslot, wgtslot, yprm);
  k_combine<<<2048, 256, 0, stream>>>(yprm, slot_tk, out);
  k_finalize<<<1, 64, 0, stream>>>(counts, psum, scal, out);
}

// Round 19
// 141.061 us; speedup vs baseline: 1.1673x; 1.0594x over previous
//
#include <hip/hip_runtime.h>
#include <hip/hip_bf16.h>

#define T_TOKENS 2048
#define D_EMBD 768
#define N_EXP 64
#define EW 256
#define TOPK 8
#define TW (N_EXP*EW)
#define PAD_SLOTS 20480   // 16384 + 64*63 rounded up to 64-tile granularity
#define SCHED_MAX 2560    // 8 * 320 worst-case positions, mult of 512
#define OUT_BASE (2048*768)

typedef __attribute__((ext_vector_type(8))) short bf16x8;
typedef __attribute__((ext_vector_type(4))) float f32x4;

typedef __attribute__((address_space(1))) void GAS;
typedef __attribute__((address_space(3))) void LAS;
#define GLOAD16(g, l) __builtin_amdgcn_global_load_lds((GAS*)(g), (LAS*)(l), 16, 0, 0)

__device__ inline unsigned short f2bu(float f) {
  union { __hip_bfloat16 b; unsigned short u; } cv; cv.b = __float2bfloat16(f); return cv.u;
}
__device__ inline unsigned int pk2(float a, float b) {
  return (unsigned int)f2bu(a) | ((unsigned int)f2bu(b) << 16);
}

// ---------------- init ----------------
__global__ void k_init(int* counts, int* cursor, float* psum, float* scal,
                       float* wgt_slot, int* tok_slot, int* sched_e) {
  int i = blockIdx.x*256 + threadIdx.x;   // 20480 threads
  if (i < N_EXP) { counts[i] = 0; cursor[i] = 0; psum[i] = 0.f; }
  if (i < 2) scal[i] = 0.f;
  if (i < PAD_SLOTS) { wgt_slot[i] = 0.f; tok_slot[i] = 0; }
  if (i < SCHED_MAX) sched_e[i] = -1;
}

// ---------------- router logits GEMM: lp[kc][t][e] partial sums ----------------
__global__ __launch_bounds__(256) void k_logits(const float* __restrict__ x,
                                                const float* __restrict__ rw,
                                                float* __restrict__ lp) {
  __shared__ float rw_s[8][256];
  int tid = threadIdx.x;
  int tg = blockIdx.x, eg = blockIdx.y, kc = blockIdx.z;
  #pragma unroll
  for (int idx = 0; idx < 8; idx++)
    rw_s[idx][tid] = rw[(size_t)(eg*8 + idx)*D_EMBD + kc*256 + tid];
  __syncthreads();
  int tok = tg*256 + tid;
  const float4* x4 = reinterpret_cast<const float4*>(x + (size_t)tok*D_EMBD + kc*256);
  float acc[8];
  #pragma unroll
  for (int e = 0; e < 8; e++) acc[e] = 0.f;
  #pragma unroll 4
  for (int k4 = 0; k4 < 64; k4++) {
    float4 xv = x4[k4];
    #pragma unroll
    for (int e = 0; e < 8; e++)
      acc[e] += xv.x*rw_s[e][k4*4+0] + xv.y*rw_s[e][k4*4+1]
              + xv.z*rw_s[e][k4*4+2] + xv.w*rw_s[e][k4*4+3];
  }
  float* dst = lp + (size_t)kc*T_TOKENS*N_EXP + (size_t)tok*N_EXP + eg*8;
  float4 o0 = {acc[0], acc[1], acc[2], acc[3]};
  float4 o1 = {acc[4], acc[5], acc[6], acc[7]};
  reinterpret_cast<float4*>(dst)[0] = o0;
  reinterpret_cast<float4*>(dst)[1] = o1;
}

// ---------------- router part 2: sigmoid, parallel-rank top-8, losses ----------------
__global__ __launch_bounds__(256) void k_router2(const float* __restrict__ lp,
                          int* __restrict__ sel_e, float* __restrict__ sel_w,
                          int* __restrict__ counts, float* __restrict__ psum,
                          float* __restrict__ scal) {
  __shared__ float psum_s[4][64];
  __shared__ int cnt_s[4][64];
  int tid = threadIdx.x, wv = tid >> 6, lane = tid & 63;
  float pacc = 0.f, zacc = 0.f;
  int cacc = 0;
  int tbase = blockIdx.x*8 + wv*2;
  #pragma unroll
  for (int it = 0; it < 2; it++) {
    int t = tbase + it;
    float logit = lp[(size_t)t*N_EXP + lane]
                + lp[(size_t)T_TOKENS*N_EXP + (size_t)t*N_EXP + lane]
                + lp[2*(size_t)T_TOKENS*N_EXP + (size_t)t*N_EXP + lane];
    float prob = 1.f/(1.f + expf(-logit));
    pacc += prob;
    float mx = logit;
    for (int s = 32; s; s >>= 1) mx = fmaxf(mx, __shfl_xor(mx, s, 64));
    float sse = expf(logit - mx);
    for (int s = 32; s; s >>= 1) sse += __shfl_xor(sse, s, 64);
    float lse = mx + logf(sse);
    zacc += lse*lse;
    int rank = 0;
    #pragma unroll
    for (int j = 0; j < 64; j++) {
      float pj = __shfl(prob, j, 64);
      rank += (pj > prob || (pj == prob && j < lane)) ? 1 : 0;
    }
    bool sel = rank < TOPK;
    float sp = sel ? prob : 0.f;
    for (int s = 32; s; s >>= 1) sp += __shfl_xor(sp, s, 64);
    if (sel) {
      sel_e[t*TOPK + rank] = lane;
      sel_w[t*TOPK + rank] = prob / (sp + 1e-20f);
      cacc++;
    }
  }
  psum_s[wv][lane] = pacc;
  cnt_s[wv][lane] = cacc;
  if (lane == 0) atomicAdd(&scal[0], zacc);
  __syncthreads();
  if (tid < 64) {
    float p = psum_s[0][tid] + psum_s[1][tid] + psum_s[2][tid] + psum_s[3][tid];
    int c = cnt_s[0][tid] + cnt_s[1][tid] + cnt_s[2][tid] + cnt_s[3][tid];
    atomicAdd(&psum[tid], p);
    atomicAdd(&counts[tid], c);
  }
}

// ---------------- schedule: 64-row tiles, XCD-grouped positions ----------------
__global__ void k_schedule(const int* __restrict__ counts, int* __restrict__ offsets,
                           int* __restrict__ sched_e, int* __restrict__ sched_r0) {
  int e = threadIdx.x;   // 64 threads, one wave
  int c = counts[e];
  int tiles = (c + 63) >> 6;
  int padded = tiles << 6;
  int ip = padded;
  for (int s = 1; s < 64; s <<= 1) { int v = __shfl_up(ip, s, 64); if (e >= s) ip += v; }
  int rowoff = ip - padded;
  offsets[e] = rowoff;
  int it = tiles;
  for (int s = 8; s < 64; s <<= 1) { int v = __shfl_up(it, s, 64); if (e >= s) it += v; }
  int rank = it - tiles;
  int xcd = e & 7;
  for (int i = 0; i < tiles; i++) {
    int p = xcd + 8*(rank + i);
    sched_e[p] = e;
    sched_r0[p] = rowoff + i*64;
  }
}

// ---------------- assign tokens to slots ----------------
__global__ void k_assign(const int* __restrict__ sel_e, const float* __restrict__ sel_w,
                         const int* __restrict__ offsets, int* __restrict__ cursor,
                         int* __restrict__ tok_slot, float* __restrict__ wgt_slot,
                         int* __restrict__ slot_tk) {
  int i = blockIdx.x*256 + threadIdx.x;   // 16384
  int e = sel_e[i];
  int pos = atomicAdd(&cursor[e], 1);
  int slot = offsets[e] + pos;
  tok_slot[slot] = i >> 3;
  wgt_slot[slot] = sel_w[i];
  slot_tk[i] = slot;
}

// ---------------- grouped GEMM with fused fp32->bf16 convert+transpose staging ----------------
// 64x128 tile, BK=64, double-buffered (round-12 verified best).
// B staging (conflict-free): thread (n4=tid&31, kpb=tid>>5) loads 8 consecutive fp32
// k-rows of its col-quad, packs each col's 8 k's into one uint4, single b128 write to
// row n, chunk (kpb ^ S(n)), S(n) = (n&7)^((n>>3)&7). 2-way per 16-lane group = free.
template<int MODE>
__global__ __launch_bounds__(256) void k_moe_gemm(
    const void* __restrict__ Asrc, const float* __restrict__ Bsrc,
    const int* __restrict__ sched_e, const int* __restrict__ sched_r0,
    const int* __restrict__ tok_slot, const float* __restrict__ wgt_slot,
    __hip_bfloat16* __restrict__ outp) {
  constexpr int NS   = (MODE == 1) ? 12 : 4;       // K-steps of 64
  constexpr int BSTR = (MODE == 1) ? TW : D_EMBD;  // native B row stride (fp32)
  __shared__ __hip_bfloat16 As[2][64*64];
  __shared__ __hip_bfloat16 Bs[2][128*64];
  int tid = threadIdx.x;
  int nch = blockIdx.y;
  int n4 = tid & 31, kpb = tid >> 5;     // B staging: col-quad, k-octet
  int mrow = tid >> 4, k4f = tid & 15;   // A staging (MODE1)
  int arl = tid >> 3, akc = tid & 7;     // A gload (MODE2)
  int a_off = ((akc ^ (arl & 7)) << 3);
  int wv = tid >> 6, lane = tid & 63;
  int wm = wv >> 1, wn = wv & 1;
  int l15 = lane & 15, l4 = lane >> 4;

  for (int p = blockIdx.x; p < SCHED_MAX; p += gridDim.x) {
    int e = sched_e[p];
    if (e < 0) continue;
    int r0 = sched_r0[p];

    int browb = (MODE == 1) ? 0 : e*EW;                    // B k-row base
    int bcolb = (MODE == 1) ? (e*EW + nch*128) : nch*128;  // B col base

    int tks[4];
    size_t a_base0 = 0, a_base1 = 0;
    if (MODE == 1) {
      #pragma unroll
      for (int i = 0; i < 4; i++) tks[i] = tok_slot[r0 + i*16 + mrow];
    } else {
      a_base0 = (size_t)(r0 + arl) * EW;
      a_base1 = (size_t)(r0 + arl + 32) * EW;
    }

    float bv[8][4], av[4][4];

    auto B_LOAD = [&](int k0) {
      const float* rp = Bsrc + (size_t)(browb + k0 + kpb*8)*BSTR + bcolb + n4*4;
      #pragma unroll
      for (int r = 0; r < 8; r++)
        *reinterpret_cast<float4*>(&bv[r][0]) =
            *reinterpret_cast<const float4*>(rp + (size_t)r*BSTR);
    };
    auto B_WRITE = [&](int bsel) {
      char* bs = (char*)&Bs[bsel][0];
      #pragma unroll
      for (int c = 0; c < 4; c++) {
        int n = n4*4 + c;
        int ch = kpb ^ ((n & 7) ^ ((n >> 3) & 7));
        uint4 o = { pk2(bv[0][c], bv[1][c]), pk2(bv[2][c], bv[3][c]),
                    pk2(bv[4][c], bv[5][c]), pk2(bv[6][c], bv[7][c]) };
        *reinterpret_cast<uint4*>(bs + n*128 + ch*16) = o;
      }
    };
    auto A_LOAD1 = [&](int k0) {
      const float* xf = (const float*)Asrc;
      #pragma unroll
      for (int i = 0; i < 4; i++)
        *reinterpret_cast<float4*>(&av[i][0]) =
            *reinterpret_cast<const float4*>(xf + (size_t)tks[i]*D_EMBD + k0 + k4f*4);
    };
    auto A_WRITE1 = [&](int bsel) {
      char* as_ = (char*)&As[bsel][0];
      #pragma unroll
      for (int i = 0; i < 4; i++) {
        int m = i*16 + mrow;
        int ch = (k4f >> 1) ^ (m & 7);
        uint2 val = { pk2(av[i][0], av[i][1]), pk2(av[i][2], av[i][3]) };
        *reinterpret_cast<uint2*>(as_ + m*128 + ch*16 + (k4f & 1)*8) = val;
      }
    };
    auto A_GLOAD2 = [&](int bsel, int k0) {
      const __hip_bfloat16* hb = (const __hip_bfloat16*)Asrc;
      GLOAD16(hb + a_base0 + k0 + a_off, &As[bsel][0] + tid*8);
      GLOAD16(hb + a_base1 + k0 + a_off, &As[bsel][0] + (256 + tid)*8);
    };

    f32x4 acc[2][4];
    f32x4 z = {0.f, 0.f, 0.f, 0.f};
    #pragma unroll
    for (int m = 0; m < 2; m++)
      #pragma unroll
      for (int n = 0; n < 4; n++) acc[m][n] = z;

    // prologue: stage step 0 into buf 0
    if (MODE == 1) { A_LOAD1(0); B_LOAD(0); A_WRITE1(0); B_WRITE(0); }
    else           { A_GLOAD2(0, 0); B_LOAD(0); B_WRITE(0);
                     asm volatile("s_waitcnt vmcnt(0)" ::: "memory"); }
    __syncthreads();

    int cur = 0;
    for (int step = 0; step < NS; step++) {
      bool more = (step + 1 < NS);
      int k1 = (step + 1)*64;
      if (more) {
        if (MODE == 1) { A_LOAD1(k1); B_LOAD(k1); }
        else           { A_GLOAD2(cur ^ 1, k1); B_LOAD(k1); }
      }
      const char* asC = (const char*)&As[cur][0];
      const char* bsC = (const char*)&Bs[cur][0];
      bf16x8 af[2][2], bq[4][2];
      #pragma unroll
      for (int m = 0; m < 2; m++) {
        int ra = wm*32 + m*16 + l15;
        #pragma unroll
        for (int kk = 0; kk < 2; kk++)
          af[m][kk] = *reinterpret_cast<const bf16x8*>(
              asC + ra*128 + (((kk*4 + l4) ^ (ra & 7)) << 4));
      }
      #pragma unroll
      for (int n = 0; n < 4; n++) {
        int rb = wn*64 + n*16 + l15;
        int Sb = (rb & 7) ^ ((rb >> 3) & 7);
        #pragma unroll
        for (int kk = 0; kk < 2; kk++)
          bq[n][kk] = *reinterpret_cast<const bf16x8*>(
              bsC + rb*128 + (((kk*4 + l4) ^ Sb) << 4));
      }
      #pragma unroll
      for (int kk = 0; kk < 2; kk++)
        #pragma unroll
        for (int m = 0; m < 2; m++)
          #pragma unroll
          for (int n = 0; n < 4; n++)
            acc[m][n] = __builtin_amdgcn_mfma_f32_16x16x32_bf16(af[m][kk], bq[n][kk], acc[m][n], 0, 0, 0);
      if (more) {
        if (MODE == 1) { A_WRITE1(cur ^ 1); B_WRITE(cur ^ 1); }
        else           { B_WRITE(cur ^ 1);
                         asm volatile("s_waitcnt vmcnt(0)" ::: "memory"); }
      }
      __syncthreads();
      cur ^= 1;
    }

    if (MODE == 1) {
      #pragma unroll
      for (int m = 0; m < 2; m++)
        #pragma unroll
        for (int j = 0; j < 4; j++) {
          int r = r0 + wm*32 + m*16 + l4*4 + j;
          float wg = wgt_slot[r];
          #pragma unroll
          for (int n = 0; n < 4; n++) {
            int col = nch*128 + wn*64 + n*16 + l15;
            float v = fmaxf(acc[m][n][j], 0.f);
            outp[(size_t)r*EW + col] = __float2bfloat16(v*v*wg);
          }
        }
    } else {
      #pragma unroll
      for (int m = 0; m < 2; m++)
        #pragma unroll
        for (int j = 0; j < 4; j++) {
          int r = r0 + wm*32 + m*16 + l4*4 + j;
          #pragma unroll
          for (int n = 0; n < 4; n++) {
            int col = nch*128 + wn*64 + n*16 + l15;
            outp[(size_t)r*D_EMBD + col] = __float2bfloat16(acc[m][n][j]);
          }
        }
    }
  }
}

// ---------------- combine 8 expert rows per token (vectorized gather) ----------------
__global__ void k_combine(const __hip_bfloat16* __restrict__ y, const int* __restrict__ slot_tk,
                          float* __restrict__ out) {
  __shared__ int s[TOPK];
  int t = blockIdx.x, tid = threadIdx.x;
  if (tid < TOPK) s[tid] = slot_tk[t*TOPK + tid];
  __syncthreads();
  if (tid < 192) {
    int c = tid*4;
    float a0 = 0.f, a1 = 0.f, a2 = 0.f, a3 = 0.f;
    #pragma unroll
    for (int k = 0; k < TOPK; k++) {
      ushort4 v = *reinterpret_cast<const ushort4*>(&y[(size_t)s[k]*D_EMBD + c]);
      union { unsigned int u; float f; } f0, f1, f2, f3;
      f0.u = ((unsigned int)v.x) << 16;
      f1.u = ((unsigned int)v.y) << 16;
      f2.u = ((unsigned int)v.z) << 16;
      f3.u = ((unsigned int)v.w) << 16;
      a0 += f0.f; a1 += f1.f; a2 += f2.f; a3 += f3.f;
    }
    float4 o = {a0, a1, a2, a3};
    *reinterpret_cast<float4*>(&out[(size_t)t*D_EMBD + c]) = o;
  }
}

// ---------------- aux losses + f_i ----------------
__global__ void k_finalize(const int* __restrict__ counts, const float* __restrict__ psum,
                           const float* __restrict__ scal, float* __restrict__ out) {
  __shared__ float part[N_EXP], ptot[N_EXP];
  int e = threadIdx.x;
  float f = (float)counts[e] / 16384.f;
  float p = psum[e] / 2048.f;
  part[e] = f * p;
  ptot[e] = p;
  out[OUT_BASE + 3 + e] = f;
  __syncthreads();
  if (e == 0) {
    float s = 0.f, q = 0.f;
    for (int i = 0; i < N_EXP; i++) { s += part[i]; q += ptot[i]; }
    out[OUT_BASE + 0] = scal[0] / 2048.f;      // router_z_loss
    out[OUT_BASE + 1] = 64.f * s;              // load_balance_loss
    out[OUT_BASE + 2] = q;                     // compute_loss
  }
}

extern "C" void kernel_launch(void* const* d_in, const int* in_sizes, int n_in,
                              void* d_out, int out_size, void* d_ws, size_t ws_size,
                              hipStream_t stream) {
  const float* x  = (const float*)d_in[0];
  const float* rw = (const float*)d_in[1];
  const float* w1 = (const float*)d_in[2];
  const float* w2 = (const float*)d_in[3];
  float* out = (float*)d_out;
  char* ws = (char*)d_ws;

  size_t o = 0;
  auto alloc = [&](size_t b) { size_t r = o; o += (b + 255) & ~(size_t)255; return r; };
  __hip_bfloat16* hprm  = (__hip_bfloat16*)(ws + alloc((size_t)PAD_SLOTS*256*2));
  __hip_bfloat16* yprm  = (__hip_bfloat16*)(ws + alloc((size_t)PAD_SLOTS*768*2));
  float* lp      = (float*)(ws + alloc(3UL*2048*64*4));
  int*   sel_e   = (int*)  (ws + alloc(16384UL*4));
  float* sel_w   = (float*)(ws + alloc(16384UL*4));
  int*   slot_tk = (int*)  (ws + alloc(16384UL*4));
  int*   tokslot = (int*)  (ws + alloc((size_t)PAD_SLOTS*4));
  float* wgtslot = (float*)(ws + alloc((size_t)PAD_SLOTS*4));
  int*   counts  = (int*)  (ws + alloc(256));
  int*   cursor  = (int*)  (ws + alloc(256));
  float* psum    = (float*)(ws + alloc(256));
  float* scal    = (float*)(ws + alloc(256));
  int*   offsets = (int*)  (ws + alloc(256));
  int*   sch_e   = (int*)  (ws + alloc(SCHED_MAX*4));
  int*   sch_r0  = (int*)  (ws + alloc(SCHED_MAX*4));

  k_init<<<80, 256, 0, stream>>>(counts, cursor, psum, scal, wgtslot, tokslot, sch_e);
  k_logits<<<dim3(8, 8, 3), 256, 0, stream>>>(x, rw, lp);
  k_router2<<<256, 256, 0, stream>>>(lp, sel_e, sel_w, counts, psum, scal);
  k_schedule<<<1, 64, 0, stream>>>(counts, offsets, sch_e, sch_r0);
  k_assign<<<64, 256, 0, stream>>>(sel_e, sel_w, offsets, cursor, tokslot, wgtslot, slot_tk);
  k_moe_gemm<1><<<dim3(512, 2), 256, 0, stream>>>((const void*)x, w1, sch_e, sch_r0, tokslot, wgtslot, hprm);
  k_moe_gemm<2><<<dim3(512, 6), 256, 0, stream>>>((const void*)hprm, w2, sch_e, sch_r0, tokslot, wgtslot, yprm);
  k_combine<<<2048, 256, 0, stream>>>(yprm, slot_tk, out);
  k_finalize<<<1, 64, 0, stream>>>(counts, psum, scal, out);
}